// Round 1
// baseline (689.306 us; speedup 1.0000x reference)
//
#include <hip/hip_runtime.h>
#include <hip/hip_bf16.h>

#define DIM 128
#define N_OUT_ROWS 100000

typedef __attribute__((ext_vector_type(8))) __bf16 bf16x8;
typedef __attribute__((ext_vector_type(4))) float f32x4;

// ---------------------------------------------------------------------------
// Probe: decide whether index buffer is int32 or int64.
// If int64 (values < 2^31), every odd 32-bit word is 0. For a random int32
// index array over [0,100000), the OR of 800K odd words is ~never 0.
// Writes 1 to *flag if any odd word is nonzero (=> int32 layout).
// ---------------------------------------------------------------------------
__global__ void idx_probe_kernel(const unsigned* __restrict__ idx32,
                                 unsigned* __restrict__ flag, int n) {
  unsigned v = 0;
  const int stride = gridDim.x * blockDim.x;
  for (int i = blockIdx.x * blockDim.x + threadIdx.x; i < n; i += stride)
    v |= idx32[2 * i + 1];
  if (v) atomicOr(flag, 1u);
}

// ---------------------------------------------------------------------------
// Fused: h = relu(e @ W^T + b); atomic segment-sum into out[index[n]].
// Per wave: 16 e-rows. 8 N-tiles (k0) x 4 K-steps (t) of mfma_f32_16x16x32_bf16.
// A frag (lane l, elem i): e[n0 + (l&15)][32t + (l>>4)*8 + i]
// B frag (lane l, elem i): W[k0*16 + (l&15)][32t + (l>>4)*8 + i]
// C/D (lane l, reg r):     h[n0 + (l>>4)*4 + r][k0*16 + (l&15)]   (m89 layout)
// ---------------------------------------------------------------------------
__global__ __launch_bounds__(256, 2) void fused_gemm_scatter(
    const float* __restrict__ e, const int* __restrict__ idx,
    const float* __restrict__ W, const float* __restrict__ bias_p,
    float* __restrict__ out, const unsigned* __restrict__ flag,
    int n_chunks) {
  const int tid = threadIdx.x;
  const int wave = tid >> 6;
  const int lane = tid & 63;
  const int lr = lane & 15;  // M/N selector within fragment
  const int lg = lane >> 4;  // K-group / row-group selector

  const bool idx64 = (*flag == 0u);

  // Preload all B fragments (W as bf16) into registers: 4 K-steps x 8 N-tiles.
  bf16x8 bfrag[4][8];
#pragma unroll
  for (int k0 = 0; k0 < 8; ++k0) {
    const float* wrow = W + (size_t)(k0 * 16 + lr) * DIM + lg * 8;
#pragma unroll
    for (int t = 0; t < 4; ++t) {
      f32x4 w0 = *(const f32x4*)(wrow + t * 32);
      f32x4 w1 = *(const f32x4*)(wrow + t * 32 + 4);
      bf16x8 f;
      f[0] = (__bf16)w0[0]; f[1] = (__bf16)w0[1];
      f[2] = (__bf16)w0[2]; f[3] = (__bf16)w0[3];
      f[4] = (__bf16)w1[0]; f[5] = (__bf16)w1[1];
      f[6] = (__bf16)w1[2]; f[7] = (__bf16)w1[3];
      bfrag[t][k0] = f;
    }
  }
  // Bias: each lane needs b[k0*16 + lr] for its output column.
  float bias[8];
#pragma unroll
  for (int k0 = 0; k0 < 8; ++k0) bias[k0] = bias_p[k0 * 16 + lr];

  for (int chunk = blockIdx.x; chunk < n_chunks; chunk += gridDim.x) {
    const int n0 = chunk * 64 + wave * 16;

    // Load + convert this wave's 16x128 e-tile into 4 A fragments.
    const float* erow = e + (size_t)(n0 + lr) * DIM + lg * 8;
    bf16x8 afrag[4];
#pragma unroll
    for (int t = 0; t < 4; ++t) {
      f32x4 a0 = *(const f32x4*)(erow + t * 32);
      f32x4 a1 = *(const f32x4*)(erow + t * 32 + 4);
      bf16x8 f;
      f[0] = (__bf16)a0[0]; f[1] = (__bf16)a0[1];
      f[2] = (__bf16)a0[2]; f[3] = (__bf16)a0[3];
      f[4] = (__bf16)a1[0]; f[5] = (__bf16)a1[1];
      f[6] = (__bf16)a1[2]; f[7] = (__bf16)a1[3];
      afrag[t] = f;
    }

    f32x4 acc[8];
#pragma unroll
    for (int k0 = 0; k0 < 8; ++k0) acc[k0] = (f32x4){0.f, 0.f, 0.f, 0.f};
#pragma unroll
    for (int t = 0; t < 4; ++t) {
#pragma unroll
      for (int k0 = 0; k0 < 8; ++k0) {
        acc[k0] = __builtin_amdgcn_mfma_f32_16x16x32_bf16(
            afrag[t], bfrag[t][k0], acc[k0], 0, 0, 0);
      }
    }

    // bias + ReLU + atomic scatter. Lane l, reg r owns
    // h[n0 + lg*4 + r][k0*16 + lr].
#pragma unroll
    for (int r = 0; r < 4; ++r) {
      const int n = n0 + lg * 4 + r;
      const int row = idx64 ? idx[2 * n] : idx[n];
      float* orow = out + (size_t)row * DIM + lr;
#pragma unroll
      for (int k0 = 0; k0 < 8; ++k0) {
        float v = fmaxf(acc[k0][r] + bias[k0], 0.f);
        unsafeAtomicAdd(orow + k0 * 16, v);
      }
    }
  }
}

extern "C" void kernel_launch(void* const* d_in, const int* in_sizes, int n_in,
                              void* d_out, int out_size, void* d_ws, size_t ws_size,
                              hipStream_t stream) {
  const float* e = (const float*)d_in[0];
  const int* idx = (const int*)d_in[1];
  const float* W = (const float*)d_in[2];
  const float* b = (const float*)d_in[3];
  float* out = (float*)d_out;
  unsigned* flag = (unsigned*)d_ws;

  const int n_e = in_sizes[0] / DIM;  // 1,600,000 rows

  hipMemsetAsync(d_out, 0, (size_t)out_size * sizeof(float), stream);
  hipMemsetAsync(flag, 0, sizeof(unsigned), stream);

  idx_probe_kernel<<<256, 256, 0, stream>>>((const unsigned*)idx, flag, n_e / 2);

  const int n_chunks = n_e / 64;  // 25,000 chunks of 64 rows
  fused_gemm_scatter<<<512, 256, 0, stream>>>(e, idx, W, b, out, flag, n_chunks);
}